// Round 6
// baseline (2682.715 us; speedup 1.0000x reference)
//
#include <hip/hip_runtime.h>
#include <hip/hip_bf16.h>

#define IN_DIM 64
#define OUT_DIM 64

typedef float nt_f4 __attribute__((ext_vector_type(4)));   // for nontemporal builtins

// ---------------------------------------------------------------------------
// Kernel 1: h = ReLU(features @ q_w + q_b); hn = 0; counts = 0.
// 4 threads per row; thread owns 16 output cols (4 x float4 acc). No LDS.
// ---------------------------------------------------------------------------
__global__ __launch_bounds__(256) void proj_kernel(
    const float4* __restrict__ feat4, const float4* __restrict__ qw4,
    const float4* __restrict__ qb4, float4* __restrict__ h4,
    float4* __restrict__ hn4, int* __restrict__ counts, int n) {
    const size_t gtid = blockIdx.x * (size_t)256 + threadIdx.x;
    const int row = (int)(gtid >> 2);
    const int sub = (int)(gtid & 3);          // which 16-col chunk
    if (row >= n) return;

    float4 acc[4];
    #pragma unroll
    for (int m = 0; m < 4; ++m) acc[m] = qb4[sub * 4 + m];

    #pragma unroll
    for (int k4 = 0; k4 < 16; ++k4) {
        const float4 xv = feat4[(size_t)row * 16 + k4];
        #pragma unroll
        for (int j = 0; j < 4; ++j) {
            const int k = k4 * 4 + j;
            const float xs = (j == 0) ? xv.x : (j == 1) ? xv.y : (j == 2) ? xv.z : xv.w;
            #pragma unroll
            for (int m = 0; m < 4; ++m) {
                const float4 w = qw4[k * 16 + sub * 4 + m];
                acc[m].x = fmaf(xs, w.x, acc[m].x);
                acc[m].y = fmaf(xs, w.y, acc[m].y);
                acc[m].z = fmaf(xs, w.z, acc[m].z);
                acc[m].w = fmaf(xs, w.w, acc[m].w);
            }
        }
    }
    if (sub == 0) counts[row] = 0;            // zero CSR histogram in same pass
    const float4 zero = make_float4(0.f, 0.f, 0.f, 0.f);
    #pragma unroll
    for (int m = 0; m < 4; ++m) {
        const size_t o = (size_t)row * 16 + sub * 4 + m;
        float4 r = acc[m];
        r.x = fmaxf(r.x, 0.f); r.y = fmaxf(r.y, 0.f);
        r.z = fmaxf(r.z, 0.f); r.w = fmaxf(r.w, 0.f);
        h4[o]  = r;
        hn4[o] = zero;          // zero atomic-path aggregation buffer
    }
}

// ---------------------------------------------------------------------------
// Kernel 2 (ATOMIC PATH): hn[dst] += h[src] * alpha.
// 16 lanes per edge, float4 per lane. Native f32 atomics via unsafeAtomicAdd.
// ---------------------------------------------------------------------------
__global__ __launch_bounds__(256) void scatter_kernel(
    const float4* __restrict__ h4, const float* __restrict__ alpha,
    const int* __restrict__ src, const int* __restrict__ dst,
    float* __restrict__ hn, int nE) {
    const size_t gtid = blockIdx.x * (size_t)256 + threadIdx.x;
    const int eid = (int)(gtid >> 4);
    const int c4  = (int)(gtid & 15);
    if (eid >= nE) return;

    const int   s = __builtin_nontemporal_load(&src[eid]);
    const int   d = __builtin_nontemporal_load(&dst[eid]);
    const float a = __builtin_nontemporal_load(&alpha[eid]);

    const float4 v = h4[(size_t)s * 16 + c4];
    float* p = &hn[(size_t)d * IN_DIM + c4 * 4];
    unsafeAtomicAdd(p + 0, v.x * a);
    unsafeAtomicAdd(p + 1, v.y * a);
    unsafeAtomicAdd(p + 2, v.z * a);
    unsafeAtomicAdd(p + 3, v.w * a);
}

// ---------------------------------------------------------------------------
// CSR PATH (experiment; output does NOT depend on it, all indices clamped so
// it cannot fault regardless of logic bugs).
// ---------------------------------------------------------------------------
__global__ __launch_bounds__(256) void count_kernel(
    const int* __restrict__ dst, int* __restrict__ counts, int n, int nE) {
    const int e = blockIdx.x * 256 + threadIdx.x;
    if (e >= nE) return;
    int d = dst[e];
    d = ((unsigned)d < (unsigned)n) ? d : 0;
    atomicAdd(&counts[d], 1);
}

// per-block inclusive scan -> exclusive offsets + block sums
__global__ __launch_bounds__(256) void scan1_kernel(
    const int* __restrict__ counts, int* __restrict__ offsets,
    int* __restrict__ blocksums, int n) {
    __shared__ int s[256];
    const int tid = threadIdx.x;
    const int i = blockIdx.x * 256 + tid;
    const int v = (i < n) ? counts[i] : 0;
    s[tid] = v;
    __syncthreads();
    #pragma unroll
    for (int off = 1; off < 256; off <<= 1) {
        const int t = (tid >= off) ? s[tid - off] : 0;
        __syncthreads();
        s[tid] += t;
        __syncthreads();
    }
    if (i < n) offsets[i] = s[tid] - v;          // exclusive within block
    if (tid == 255) blocksums[blockIdx.x] = s[255];
}

// single-block exclusive scan of block sums (nb <= 512)
__global__ __launch_bounds__(512) void scan2_kernel(int* __restrict__ blocksums, int nb) {
    __shared__ int s[512];
    const int tid = threadIdx.x;
    const int v = (tid < nb) ? blocksums[tid] : 0;
    s[tid] = v;
    __syncthreads();
    #pragma unroll
    for (int off = 1; off < 512; off <<= 1) {
        const int t = (tid >= off) ? s[tid - off] : 0;
        __syncthreads();
        s[tid] += t;
        __syncthreads();
    }
    if (tid < nb) blocksums[tid] = s[tid] - v;   // exclusive
}

__global__ __launch_bounds__(256) void scan3_kernel(
    int* __restrict__ offsets, int* __restrict__ cursor,
    const int* __restrict__ blocksums, int n, int nE) {
    const int i = blockIdx.x * 256 + threadIdx.x;
    if (i < n) {
        const int o = offsets[i] + blocksums[blockIdx.x];
        offsets[i] = o;
        cursor[i]  = o;
    }
    if (i == 0) offsets[n] = nE;
}

__global__ __launch_bounds__(256) void fill_kernel(
    const int* __restrict__ dst, int* __restrict__ cursor,
    int* __restrict__ eidx, int n, int nE) {
    const int e = blockIdx.x * 256 + threadIdx.x;
    if (e >= nE) return;
    int d = dst[e];
    d = ((unsigned)d < (unsigned)n) ? d : 0;
    const int p = atomicAdd(&cursor[d], 1);
    if ((unsigned)p < (unsigned)nE) eidx[p] = e;
}

// one wave per node, lane = dim; atomic-free aggregation into hn2
__global__ __launch_bounds__(256) void agg_kernel(
    const float* __restrict__ h, const float* __restrict__ alpha,
    const int* __restrict__ src, const int* __restrict__ eidx,
    const int* __restrict__ offsets, float* __restrict__ hn2, int n, int nE) {
    const size_t gtid = blockIdx.x * (size_t)256 + threadIdx.x;
    const int v = (int)(gtid >> 6);
    const int lane = (int)(gtid & 63);
    if (v >= n) return;
    int b  = offsets[v];
    int e1 = offsets[v + 1];
    if (b < 0) b = 0;
    if (e1 > nE) e1 = nE;
    float acc = 0.f;
    for (int j = b; j < e1; ++j) {
        int e = eidx[j];
        e = ((unsigned)e < (unsigned)nE) ? e : 0;
        int s = src[e];
        s = ((unsigned)s < (unsigned)n) ? s : 0;
        acc = fmaf(h[(size_t)s * IN_DIM + lane], alpha[e], acc);
    }
    hn2[(size_t)v * IN_DIM + lane] = acc;
}

// ---------------------------------------------------------------------------
// Kernel 3: z = ReLU(concat([h, hn]) @ w_w + w_b); out = z / ||z||_2.
// ---------------------------------------------------------------------------
__global__ __launch_bounds__(256) void out_kernel(
    const float4* __restrict__ h4, const float4* __restrict__ hn4,
    const float4* __restrict__ ww4, const float4* __restrict__ wb4,
    float4* __restrict__ out4, int n) {
    const size_t gtid = blockIdx.x * (size_t)256 + threadIdx.x;
    const int row = (int)(gtid >> 2);
    const int sub = (int)(gtid & 3);
    if (row >= n) return;

    float4 acc[4];
    #pragma unroll
    for (int m = 0; m < 4; ++m) acc[m] = wb4[sub * 4 + m];

    #pragma unroll
    for (int k4 = 0; k4 < 16; ++k4) {
        const float4 xv = h4[(size_t)row * 16 + k4];
        #pragma unroll
        for (int j = 0; j < 4; ++j) {
            const int k = k4 * 4 + j;
            const float xs = (j == 0) ? xv.x : (j == 1) ? xv.y : (j == 2) ? xv.z : xv.w;
            #pragma unroll
            for (int m = 0; m < 4; ++m) {
                const float4 w = ww4[k * 16 + sub * 4 + m];
                acc[m].x = fmaf(xs, w.x, acc[m].x);
                acc[m].y = fmaf(xs, w.y, acc[m].y);
                acc[m].z = fmaf(xs, w.z, acc[m].z);
                acc[m].w = fmaf(xs, w.w, acc[m].w);
            }
        }
    }
    #pragma unroll
    for (int k4 = 0; k4 < 16; ++k4) {
        const float4 xv = hn4[(size_t)row * 16 + k4];
        #pragma unroll
        for (int j = 0; j < 4; ++j) {
            const int k = 64 + k4 * 4 + j;
            const float xs = (j == 0) ? xv.x : (j == 1) ? xv.y : (j == 2) ? xv.z : xv.w;
            #pragma unroll
            for (int m = 0; m < 4; ++m) {
                const float4 w = ww4[k * 16 + sub * 4 + m];
                acc[m].x = fmaf(xs, w.x, acc[m].x);
                acc[m].y = fmaf(xs, w.y, acc[m].y);
                acc[m].z = fmaf(xs, w.z, acc[m].z);
                acc[m].w = fmaf(xs, w.w, acc[m].w);
            }
        }
    }

    float sq = 0.f;
    #pragma unroll
    for (int m = 0; m < 4; ++m) {
        acc[m].x = fmaxf(acc[m].x, 0.f); acc[m].y = fmaxf(acc[m].y, 0.f);
        acc[m].z = fmaxf(acc[m].z, 0.f); acc[m].w = fmaxf(acc[m].w, 0.f);
        sq = fmaf(acc[m].x, acc[m].x, sq);
        sq = fmaf(acc[m].y, acc[m].y, sq);
        sq = fmaf(acc[m].z, acc[m].z, sq);
        sq = fmaf(acc[m].w, acc[m].w, sq);
    }
    sq += __shfl_xor(sq, 1, 64);
    sq += __shfl_xor(sq, 2, 64);
    const float inv = 1.0f / sqrtf(sq);

    #pragma unroll
    for (int m = 0; m < 4; ++m) {
        nt_f4 r;
        r.x = acc[m].x * inv; r.y = acc[m].y * inv;
        r.z = acc[m].z * inv; r.w = acc[m].w * inv;
        __builtin_nontemporal_store(r, (nt_f4*)&out4[(size_t)row * 16 + sub * 4 + m]);
    }
}

extern "C" void kernel_launch(void* const* d_in, const int* in_sizes, int n_in,
                              void* d_out, int out_size, void* d_ws, size_t ws_size,
                              hipStream_t stream) {
    const float* feat  = (const float*)d_in[0];
    const float* qw    = (const float*)d_in[1];
    const float* qb    = (const float*)d_in[2];
    const float* ww    = (const float*)d_in[3];
    const float* wb    = (const float*)d_in[4];
    const float* alpha = (const float*)d_in[5];
    const int*   src   = (const int*)d_in[6];
    const int*   dst   = (const int*)d_in[7];
    float* out = (float*)d_out;

    const int n  = in_sizes[0] / IN_DIM;   // 100000
    const int nE = in_sizes[5];            // 1600000
    const int NB = (n + 255) / 256;        // 391

    // workspace layout
    float* h   = (float*)d_ws;                       // n*64 f32
    float* hn  = h + (size_t)n * IN_DIM;             // n*64 f32
    float* hn2 = hn + (size_t)n * IN_DIM;            // n*64 f32 (CSR result)
    int* counts    = (int*)(hn2 + (size_t)n * IN_DIM);
    int* offsets   = counts + n;                     // n+1
    int* cursor    = offsets + (n + 1);              // n
    int* blocksums = cursor + n;                     // NB
    int* eidx      = blocksums + NB;                 // nE
    const size_t needed = (size_t)((char*)(eidx + nE) - (char*)d_ws);
    const bool do_csr = ws_size >= needed;

    // 1) projection + zero hn + zero counts
    proj_kernel<<<(int)(((long long)n * 4 + 255) / 256), 256, 0, stream>>>(
        (const float4*)feat, (const float4*)qw, (const float4*)qb,
        (float4*)h, (float4*)hn, counts, n);

    // 2) ATOMIC PATH scatter (canonical result)
    scatter_kernel<<<(int)(((long long)nE * 16 + 255) / 256), 256, 0, stream>>>(
        (const float4*)h, alpha, src, dst, hn, nE);

    // 2b) CSR PATH (timed experiment; result in hn2, unused by output)
    if (do_csr) {
        count_kernel<<<(nE + 255) / 256, 256, 0, stream>>>(dst, counts, n, nE);
        scan1_kernel<<<NB, 256, 0, stream>>>(counts, offsets, blocksums, n);
        scan2_kernel<<<1, 512, 0, stream>>>(blocksums, NB);
        scan3_kernel<<<NB, 256, 0, stream>>>(offsets, cursor, blocksums, n, nE);
        fill_kernel<<<(nE + 255) / 256, 256, 0, stream>>>(dst, cursor, eidx, n, nE);
        agg_kernel<<<(int)(((long long)n * 64 + 255) / 256), 256, 0, stream>>>(
            h, alpha, src, eidx, offsets, hn2, n, nE);
    }

    // 3) concat GEMV + ReLU + L2 normalize (reads atomic-path hn)
    out_kernel<<<(int)(((long long)n * 4 + 255) / 256), 256, 0, stream>>>(
        (const float4*)h, (const float4*)hn, (const float4*)ww,
        (const float4*)wb, (float4*)out, n);
}

// Round 7
// 1124.606 us; speedup vs baseline: 2.3855x; 2.3855x over previous
//
#include <hip/hip_runtime.h>
#include <hip/hip_bf16.h>

#define IN_DIM 64
#define OUT_DIM 64

typedef float nt_f4 __attribute__((ext_vector_type(4)));   // for nontemporal builtins

// ---------------------------------------------------------------------------
// Kernel 1: h = ReLU(features @ q_w + q_b); counts = 0.
// 4 threads per row; thread owns 16 output cols (4 x float4 acc). No LDS.
// ---------------------------------------------------------------------------
__global__ __launch_bounds__(256) void proj_kernel(
    const float4* __restrict__ feat4, const float4* __restrict__ qw4,
    const float4* __restrict__ qb4, float4* __restrict__ h4,
    int* __restrict__ counts, int n) {
    const size_t gtid = blockIdx.x * (size_t)256 + threadIdx.x;
    const int row = (int)(gtid >> 2);
    const int sub = (int)(gtid & 3);          // which 16-col chunk
    if (row >= n) return;

    float4 acc[4];
    #pragma unroll
    for (int m = 0; m < 4; ++m) acc[m] = qb4[sub * 4 + m];

    #pragma unroll
    for (int k4 = 0; k4 < 16; ++k4) {
        const float4 xv = feat4[(size_t)row * 16 + k4];
        #pragma unroll
        for (int j = 0; j < 4; ++j) {
            const int k = k4 * 4 + j;
            const float xs = (j == 0) ? xv.x : (j == 1) ? xv.y : (j == 2) ? xv.z : xv.w;
            #pragma unroll
            for (int m = 0; m < 4; ++m) {
                const float4 w = qw4[k * 16 + sub * 4 + m];
                acc[m].x = fmaf(xs, w.x, acc[m].x);
                acc[m].y = fmaf(xs, w.y, acc[m].y);
                acc[m].z = fmaf(xs, w.z, acc[m].z);
                acc[m].w = fmaf(xs, w.w, acc[m].w);
            }
        }
    }
    if (sub == 0) counts[row] = 0;            // zero CSR histogram in same pass
    #pragma unroll
    for (int m = 0; m < 4; ++m) {
        const size_t o = (size_t)row * 16 + sub * 4 + m;
        float4 r = acc[m];
        r.x = fmaxf(r.x, 0.f); r.y = fmaxf(r.y, 0.f);
        r.z = fmaxf(r.z, 0.f); r.w = fmaxf(r.w, 0.f);
        h4[o] = r;
    }
}

// ---------------------------------------------------------------------------
// CSR build: histogram of dst
// ---------------------------------------------------------------------------
__global__ __launch_bounds__(256) void count_kernel(
    const int* __restrict__ dst, int* __restrict__ counts, int n, int nE) {
    const int e = blockIdx.x * 256 + threadIdx.x;
    if (e >= nE) return;
    int d = __builtin_nontemporal_load(&dst[e]);
    d = ((unsigned)d < (unsigned)n) ? d : 0;
    atomicAdd(&counts[d], 1);
}

// per-block inclusive scan -> exclusive offsets + block sums
__global__ __launch_bounds__(256) void scan1_kernel(
    const int* __restrict__ counts, int* __restrict__ offsets,
    int* __restrict__ blocksums, int n) {
    __shared__ int s[256];
    const int tid = threadIdx.x;
    const int i = blockIdx.x * 256 + tid;
    const int v = (i < n) ? counts[i] : 0;
    s[tid] = v;
    __syncthreads();
    #pragma unroll
    for (int off = 1; off < 256; off <<= 1) {
        const int t = (tid >= off) ? s[tid - off] : 0;
        __syncthreads();
        s[tid] += t;
        __syncthreads();
    }
    if (i < n) offsets[i] = s[tid] - v;          // exclusive within block
    if (tid == 255) blocksums[blockIdx.x] = s[255];
}

// single-block exclusive scan of block sums (nb <= 512)
__global__ __launch_bounds__(512) void scan2_kernel(int* __restrict__ blocksums, int nb) {
    __shared__ int s[512];
    const int tid = threadIdx.x;
    const int v = (tid < nb) ? blocksums[tid] : 0;
    s[tid] = v;
    __syncthreads();
    #pragma unroll
    for (int off = 1; off < 512; off <<= 1) {
        const int t = (tid >= off) ? s[tid - off] : 0;
        __syncthreads();
        s[tid] += t;
        __syncthreads();
    }
    if (tid < nb) blocksums[tid] = s[tid] - v;   // exclusive
}

__global__ __launch_bounds__(256) void scan3_kernel(
    int* __restrict__ offsets, int* __restrict__ cursor,
    const int* __restrict__ blocksums, int n, int nE) {
    const int i = blockIdx.x * 256 + threadIdx.x;
    if (i < n) {
        const int o = offsets[i] + blocksums[blockIdx.x];
        offsets[i] = o;
        cursor[i]  = o;
    }
    if (i == 0) offsets[n] = nE;
}

// bucket edges by dst: write src and alpha directly (no eidx indirection)
__global__ __launch_bounds__(256) void fill_kernel(
    const int* __restrict__ dst, const int* __restrict__ src,
    const float* __restrict__ alpha, int* __restrict__ cursor,
    int* __restrict__ srcs_s, float* __restrict__ alphas_s, int n, int nE) {
    const int e = blockIdx.x * 256 + threadIdx.x;
    if (e >= nE) return;
    int d = __builtin_nontemporal_load(&dst[e]);
    d = ((unsigned)d < (unsigned)n) ? d : 0;
    const int s = __builtin_nontemporal_load(&src[e]);
    const float a = __builtin_nontemporal_load(&alpha[e]);
    const int p = atomicAdd(&cursor[d], 1);
    if ((unsigned)p < (unsigned)nE) {
        srcs_s[p]   = s;
        alphas_s[p] = a;
    }
}

// ---------------------------------------------------------------------------
// Aggregation (atomic-free): one wave per node; 4 edges in parallel
// (quarter-wave = 16 lanes x float4 per edge -> 4 independent gather chains).
// ---------------------------------------------------------------------------
__global__ __launch_bounds__(256) void agg_kernel(
    const float4* __restrict__ h4, const float* __restrict__ alphas_s,
    const int* __restrict__ srcs_s, const int* __restrict__ offsets,
    float4* __restrict__ hn4, int n, int nE) {
    const size_t gtid = blockIdx.x * (size_t)256 + threadIdx.x;
    const int v    = (int)(gtid >> 6);
    const int lane = (int)(gtid & 63);
    const int q    = lane >> 4;        // quarter: which of 4 parallel edges
    const int c4   = lane & 15;        // float4 chunk of the 64-dim row
    if (v >= n) return;

    int b  = offsets[v];
    int e1 = offsets[v + 1];
    if (b < 0) b = 0;
    if (e1 > nE) e1 = nE;

    float4 acc = make_float4(0.f, 0.f, 0.f, 0.f);
    for (int j = b + q; j < e1; j += 4) {
        int s = srcs_s[j];
        s = ((unsigned)s < (unsigned)n) ? s : 0;
        const float a = alphas_s[j];
        const float4 hv = h4[(size_t)s * 16 + c4];
        acc.x = fmaf(hv.x, a, acc.x);
        acc.y = fmaf(hv.y, a, acc.y);
        acc.z = fmaf(hv.z, a, acc.z);
        acc.w = fmaf(hv.w, a, acc.w);
    }
    // reduce the 4 quarter-wave partials (lanes ^16, ^32): same dims per quarter
    acc.x += __shfl_xor(acc.x, 16, 64); acc.y += __shfl_xor(acc.y, 16, 64);
    acc.z += __shfl_xor(acc.z, 16, 64); acc.w += __shfl_xor(acc.w, 16, 64);
    acc.x += __shfl_xor(acc.x, 32, 64); acc.y += __shfl_xor(acc.y, 32, 64);
    acc.z += __shfl_xor(acc.z, 32, 64); acc.w += __shfl_xor(acc.w, 32, 64);

    if (q == 0) hn4[(size_t)v * 16 + c4] = acc;
}

// ---------------------------------------------------------------------------
// Fallback (only if ws too small): atomic scatter. hn must be pre-zeroed.
// ---------------------------------------------------------------------------
__global__ __launch_bounds__(256) void zero_kernel(float* __restrict__ p, size_t cnt) {
    const size_t i = blockIdx.x * (size_t)256 + threadIdx.x;
    if (i < cnt) p[i] = 0.f;
}
__global__ __launch_bounds__(256) void scatter_kernel(
    const float4* __restrict__ h4, const float* __restrict__ alpha,
    const int* __restrict__ src, const int* __restrict__ dst,
    float* __restrict__ hn, int nE) {
    const size_t gtid = blockIdx.x * (size_t)256 + threadIdx.x;
    const int eid = (int)(gtid >> 4);
    const int c4  = (int)(gtid & 15);
    if (eid >= nE) return;
    const int   s = src[eid];
    const int   d = dst[eid];
    const float a = alpha[eid];
    const float4 v = h4[(size_t)s * 16 + c4];
    float* p = &hn[(size_t)d * IN_DIM + c4 * 4];
    unsafeAtomicAdd(p + 0, v.x * a);
    unsafeAtomicAdd(p + 1, v.y * a);
    unsafeAtomicAdd(p + 2, v.z * a);
    unsafeAtomicAdd(p + 3, v.w * a);
}

// ---------------------------------------------------------------------------
// Kernel 3: z = ReLU(concat([h, hn]) @ w_w + w_b); out = z / ||z||_2.
// ---------------------------------------------------------------------------
__global__ __launch_bounds__(256) void out_kernel(
    const float4* __restrict__ h4, const float4* __restrict__ hn4,
    const float4* __restrict__ ww4, const float4* __restrict__ wb4,
    float4* __restrict__ out4, int n) {
    const size_t gtid = blockIdx.x * (size_t)256 + threadIdx.x;
    const int row = (int)(gtid >> 2);
    const int sub = (int)(gtid & 3);
    if (row >= n) return;

    float4 acc[4];
    #pragma unroll
    for (int m = 0; m < 4; ++m) acc[m] = wb4[sub * 4 + m];

    #pragma unroll
    for (int k4 = 0; k4 < 16; ++k4) {
        const float4 xv = h4[(size_t)row * 16 + k4];
        #pragma unroll
        for (int j = 0; j < 4; ++j) {
            const int k = k4 * 4 + j;
            const float xs = (j == 0) ? xv.x : (j == 1) ? xv.y : (j == 2) ? xv.z : xv.w;
            #pragma unroll
            for (int m = 0; m < 4; ++m) {
                const float4 w = ww4[k * 16 + sub * 4 + m];
                acc[m].x = fmaf(xs, w.x, acc[m].x);
                acc[m].y = fmaf(xs, w.y, acc[m].y);
                acc[m].z = fmaf(xs, w.z, acc[m].z);
                acc[m].w = fmaf(xs, w.w, acc[m].w);
            }
        }
    }
    #pragma unroll
    for (int k4 = 0; k4 < 16; ++k4) {
        const float4 xv = hn4[(size_t)row * 16 + k4];
        #pragma unroll
        for (int j = 0; j < 4; ++j) {
            const int k = 64 + k4 * 4 + j;
            const float xs = (j == 0) ? xv.x : (j == 1) ? xv.y : (j == 2) ? xv.z : xv.w;
            #pragma unroll
            for (int m = 0; m < 4; ++m) {
                const float4 w = ww4[k * 16 + sub * 4 + m];
                acc[m].x = fmaf(xs, w.x, acc[m].x);
                acc[m].y = fmaf(xs, w.y, acc[m].y);
                acc[m].z = fmaf(xs, w.z, acc[m].z);
                acc[m].w = fmaf(xs, w.w, acc[m].w);
            }
        }
    }

    float sq = 0.f;
    #pragma unroll
    for (int m = 0; m < 4; ++m) {
        acc[m].x = fmaxf(acc[m].x, 0.f); acc[m].y = fmaxf(acc[m].y, 0.f);
        acc[m].z = fmaxf(acc[m].z, 0.f); acc[m].w = fmaxf(acc[m].w, 0.f);
        sq = fmaf(acc[m].x, acc[m].x, sq);
        sq = fmaf(acc[m].y, acc[m].y, sq);
        sq = fmaf(acc[m].z, acc[m].z, sq);
        sq = fmaf(acc[m].w, acc[m].w, sq);
    }
    sq += __shfl_xor(sq, 1, 64);
    sq += __shfl_xor(sq, 2, 64);
    const float inv = 1.0f / sqrtf(sq);

    #pragma unroll
    for (int m = 0; m < 4; ++m) {
        nt_f4 r;
        r.x = acc[m].x * inv; r.y = acc[m].y * inv;
        r.z = acc[m].z * inv; r.w = acc[m].w * inv;
        __builtin_nontemporal_store(r, (nt_f4*)&out4[(size_t)row * 16 + sub * 4 + m]);
    }
}

extern "C" void kernel_launch(void* const* d_in, const int* in_sizes, int n_in,
                              void* d_out, int out_size, void* d_ws, size_t ws_size,
                              hipStream_t stream) {
    const float* feat  = (const float*)d_in[0];
    const float* qw    = (const float*)d_in[1];
    const float* qb    = (const float*)d_in[2];
    const float* ww    = (const float*)d_in[3];
    const float* wb    = (const float*)d_in[4];
    const float* alpha = (const float*)d_in[5];
    const int*   src   = (const int*)d_in[6];
    const int*   dst   = (const int*)d_in[7];
    float* out = (float*)d_out;

    const int n  = in_sizes[0] / IN_DIM;   // 100000
    const int nE = in_sizes[5];            // 1600000
    const int NB = (n + 255) / 256;        // 391

    // workspace layout
    float* h        = (float*)d_ws;                    // n*64 f32
    float* hn       = h + (size_t)n * IN_DIM;          // n*64 f32
    int*   counts   = (int*)(hn + (size_t)n * IN_DIM); // n
    int*   offsets  = counts + n;                      // n+1
    int*   cursor   = offsets + (n + 1);               // n
    int*   blocksums= cursor + n;                      // NB
    int*   srcs_s   = blocksums + NB;                  // nE
    float* alphas_s = (float*)(srcs_s + nE);           // nE
    const size_t needed = (size_t)((char*)(alphas_s + nE) - (char*)d_ws);
    const bool do_csr = ws_size >= needed;

    // 1) projection + zero counts
    proj_kernel<<<(int)(((long long)n * 4 + 255) / 256), 256, 0, stream>>>(
        (const float4*)feat, (const float4*)qw, (const float4*)qb,
        (float4*)h, counts, n);

    if (do_csr) {
        // 2) CSR build + atomic-free aggregation (canonical)
        count_kernel<<<(nE + 255) / 256, 256, 0, stream>>>(dst, counts, n, nE);
        scan1_kernel<<<NB, 256, 0, stream>>>(counts, offsets, blocksums, n);
        scan2_kernel<<<1, 512, 0, stream>>>(blocksums, NB);
        scan3_kernel<<<NB, 256, 0, stream>>>(offsets, cursor, blocksums, n, nE);
        fill_kernel<<<(nE + 255) / 256, 256, 0, stream>>>(
            dst, src, alpha, cursor, srcs_s, alphas_s, n, nE);
        agg_kernel<<<(int)(((long long)n * 64 + 255) / 256), 256, 0, stream>>>(
            (const float4*)h, alphas_s, srcs_s, offsets, (float4*)hn, n, nE);
    } else {
        // fallback: zero + atomic scatter
        const size_t cnt = (size_t)n * IN_DIM;
        zero_kernel<<<(int)((cnt + 255) / 256), 256, 0, stream>>>(hn, cnt);
        scatter_kernel<<<(int)(((long long)nE * 16 + 255) / 256), 256, 0, stream>>>(
            (const float4*)h, alpha, src, dst, hn, nE);
    }

    // 3) concat GEMV + ReLU + L2 normalize
    out_kernel<<<(int)(((long long)n * 4 + 255) / 256), 256, 0, stream>>>(
        (const float4*)h, (const float4*)hn, (const float4*)ww,
        (const float4*)wb, (float4*)out, n);
}

// Round 9
// 648.970 us; speedup vs baseline: 4.1338x; 1.7329x over previous
//
#include <hip/hip_runtime.h>
#include <hip/hip_bf16.h>

#define IN_DIM 64
#define OUT_DIM 64

typedef float nt_f4 __attribute__((ext_vector_type(4)));   // for nontemporal builtins

// ---------------------------------------------------------------------------
// Canary: 1-thread kernel launched FIRST. If rocprof attributes ~600us and
// ~1.5GB of traffic to THIS kernel next round, the "hot proj" row is an
// attribution artifact (reset/poison traffic glued to the first dispatch).
// Writes offsets[n]=nE, which scan3 later rewrites identically (harmless).
// ---------------------------------------------------------------------------
__global__ void canary_kernel(int* __restrict__ offsets, int n, int nE) {
    if (threadIdx.x == 0 && blockIdx.x == 0) offsets[n] = nE;
}

// ---------------------------------------------------------------------------
// Kernel 1: h = ReLU(features @ q_w + q_b); counts = 0.
// 4 threads per row; thread owns 16 output cols (4 x float4 acc).
// unroll capped at 4 to keep the compiler from hoisting ~64 q_w float4
// loads into registers (round-7: VGPR=256, occupancy 10%).
// ---------------------------------------------------------------------------
__global__ __launch_bounds__(256) void proj_kernel(
    const float4* __restrict__ feat4, const float4* __restrict__ qw4,
    const float4* __restrict__ qb4, float4* __restrict__ h4,
    int* __restrict__ counts, int n) {
    const size_t gtid = blockIdx.x * (size_t)256 + threadIdx.x;
    const int row = (int)(gtid >> 2);
    const int sub = (int)(gtid & 3);          // which 16-col chunk
    if (row >= n) return;

    float4 acc[4];
    #pragma unroll
    for (int m = 0; m < 4; ++m) acc[m] = qb4[sub * 4 + m];

    #pragma unroll 4
    for (int k4 = 0; k4 < 16; ++k4) {
        const float4 xv = feat4[(size_t)row * 16 + k4];
        #pragma unroll
        for (int j = 0; j < 4; ++j) {
            const int k = k4 * 4 + j;
            const float xs = (j == 0) ? xv.x : (j == 1) ? xv.y : (j == 2) ? xv.z : xv.w;
            #pragma unroll
            for (int m = 0; m < 4; ++m) {
                const float4 w = qw4[k * 16 + sub * 4 + m];
                acc[m].x = fmaf(xs, w.x, acc[m].x);
                acc[m].y = fmaf(xs, w.y, acc[m].y);
                acc[m].z = fmaf(xs, w.z, acc[m].z);
                acc[m].w = fmaf(xs, w.w, acc[m].w);
            }
        }
    }
    if (sub == 0) counts[row] = 0;            // zero CSR histogram in same pass
    #pragma unroll
    for (int m = 0; m < 4; ++m) {
        const size_t o = (size_t)row * 16 + sub * 4 + m;
        float4 r = acc[m];
        r.x = fmaxf(r.x, 0.f); r.y = fmaxf(r.y, 0.f);
        r.z = fmaxf(r.z, 0.f); r.w = fmaxf(r.w, 0.f);
        h4[o] = r;
    }
}

// ---------------------------------------------------------------------------
// CSR build: histogram of dst
// ---------------------------------------------------------------------------
__global__ __launch_bounds__(256) void count_kernel(
    const int* __restrict__ dst, int* __restrict__ counts, int n, int nE) {
    const int e = blockIdx.x * 256 + threadIdx.x;
    if (e >= nE) return;
    int d = __builtin_nontemporal_load(&dst[e]);
    d = ((unsigned)d < (unsigned)n) ? d : 0;
    atomicAdd(&counts[d], 1);
}

// per-block inclusive scan -> exclusive offsets + block sums
__global__ __launch_bounds__(256) void scan1_kernel(
    const int* __restrict__ counts, int* __restrict__ offsets,
    int* __restrict__ blocksums, int n) {
    __shared__ int s[256];
    const int tid = threadIdx.x;
    const int i = blockIdx.x * 256 + tid;
    const int v = (i < n) ? counts[i] : 0;
    s[tid] = v;
    __syncthreads();
    #pragma unroll
    for (int off = 1; off < 256; off <<= 1) {
        const int t = (tid >= off) ? s[tid - off] : 0;
        __syncthreads();
        s[tid] += t;
        __syncthreads();
    }
    if (i < n) offsets[i] = s[tid] - v;          // exclusive within block
    if (tid == 255) blocksums[blockIdx.x] = s[255];
}

// single-block exclusive scan of block sums (nb <= 512)
__global__ __launch_bounds__(512) void scan2_kernel(int* __restrict__ blocksums, int nb) {
    __shared__ int s[512];
    const int tid = threadIdx.x;
    const int v = (tid < nb) ? blocksums[tid] : 0;
    s[tid] = v;
    __syncthreads();
    #pragma unroll
    for (int off = 1; off < 512; off <<= 1) {
        const int t = (tid >= off) ? s[tid - off] : 0;
        __syncthreads();
        s[tid] += t;
        __syncthreads();
    }
    if (tid < nb) blocksums[tid] = s[tid] - v;   // exclusive
}

__global__ __launch_bounds__(256) void scan3_kernel(
    int* __restrict__ offsets, int* __restrict__ cursor,
    const int* __restrict__ blocksums, int n, int nE) {
    const int i = blockIdx.x * 256 + threadIdx.x;
    if (i < n) {
        const int o = offsets[i] + blocksums[blockIdx.x];
        offsets[i] = o;
        cursor[i]  = o;
    }
    if (i == 0) offsets[n] = nE;
}

// bucket edges by dst: write src and alpha directly (no eidx indirection)
__global__ __launch_bounds__(256) void fill_kernel(
    const int* __restrict__ dst, const int* __restrict__ src,
    const float* __restrict__ alpha, int* __restrict__ cursor,
    int* __restrict__ srcs_s, float* __restrict__ alphas_s, int n, int nE) {
    const int e = blockIdx.x * 256 + threadIdx.x;
    if (e >= nE) return;
    int d = __builtin_nontemporal_load(&dst[e]);
    d = ((unsigned)d < (unsigned)n) ? d : 0;
    const int s = __builtin_nontemporal_load(&src[e]);
    const float a = __builtin_nontemporal_load(&alpha[e]);
    const int p = atomicAdd(&cursor[d], 1);
    if ((unsigned)p < (unsigned)nE) {
        srcs_s[p]   = s;
        alphas_s[p] = a;
    }
}

// ---------------------------------------------------------------------------
// Aggregation (atomic-free): one wave per node; 4 edges in parallel
// (quarter-wave = 16 lanes x float4 per edge -> 4 independent gather chains).
// ---------------------------------------------------------------------------
__global__ __launch_bounds__(256) void agg_kernel(
    const float4* __restrict__ h4, const float* __restrict__ alphas_s,
    const int* __restrict__ srcs_s, const int* __restrict__ offsets,
    float4* __restrict__ hn4, int n, int nE) {
    const size_t gtid = blockIdx.x * (size_t)256 + threadIdx.x;
    const int v    = (int)(gtid >> 6);
    const int lane = (int)(gtid & 63);
    const int q    = lane >> 4;        // quarter: which of 4 parallel edges
    const int c4   = lane & 15;        // float4 chunk of the 64-dim row
    if (v >= n) return;

    int b  = offsets[v];
    int e1 = offsets[v + 1];
    if (b < 0) b = 0;
    if (e1 > nE) e1 = nE;

    float4 acc = make_float4(0.f, 0.f, 0.f, 0.f);
    for (int j = b + q; j < e1; j += 4) {
        int s = srcs_s[j];
        s = ((unsigned)s < (unsigned)n) ? s : 0;
        const float a = alphas_s[j];
        const float4 hv = h4[(size_t)s * 16 + c4];
        acc.x = fmaf(hv.x, a, acc.x);
        acc.y = fmaf(hv.y, a, acc.y);
        acc.z = fmaf(hv.z, a, acc.z);
        acc.w = fmaf(hv.w, a, acc.w);
    }
    // reduce the 4 quarter-wave partials (lanes ^16, ^32): same dims per quarter
    acc.x += __shfl_xor(acc.x, 16, 64); acc.y += __shfl_xor(acc.y, 16, 64);
    acc.z += __shfl_xor(acc.z, 16, 64); acc.w += __shfl_xor(acc.w, 16, 64);
    acc.x += __shfl_xor(acc.x, 32, 64); acc.y += __shfl_xor(acc.y, 32, 64);
    acc.z += __shfl_xor(acc.z, 32, 64); acc.w += __shfl_xor(acc.w, 32, 64);

    if (q == 0) hn4[(size_t)v * 16 + c4] = acc;
}

// ---------------------------------------------------------------------------
// Fallback (only if ws too small): atomic scatter. hn must be pre-zeroed.
// ---------------------------------------------------------------------------
__global__ __launch_bounds__(256) void zero_kernel(float* __restrict__ p, size_t cnt) {
    const size_t i = blockIdx.x * (size_t)256 + threadIdx.x;
    if (i < cnt) p[i] = 0.f;
}
__global__ __launch_bounds__(256) void scatter_kernel(
    const float4* __restrict__ h4, const float* __restrict__ alpha,
    const int* __restrict__ src, const int* __restrict__ dst,
    float* __restrict__ hn, int nE) {
    const size_t gtid = blockIdx.x * (size_t)256 + threadIdx.x;
    const int eid = (int)(gtid >> 4);
    const int c4  = (int)(gtid & 15);
    if (eid >= nE) return;
    const int   s = src[eid];
    const int   d = dst[eid];
    const float a = alpha[eid];
    const float4 v = h4[(size_t)s * 16 + c4];
    float* p = &hn[(size_t)d * IN_DIM + c4 * 4];
    unsafeAtomicAdd(p + 0, v.x * a);
    unsafeAtomicAdd(p + 1, v.y * a);
    unsafeAtomicAdd(p + 2, v.z * a);
    unsafeAtomicAdd(p + 3, v.w * a);
}

// ---------------------------------------------------------------------------
// Kernel 3: z = ReLU(concat([h, hn]) @ w_w + w_b); out = z / ||z||_2.
// ---------------------------------------------------------------------------
__global__ __launch_bounds__(256) void out_kernel(
    const float4* __restrict__ h4, const float4* __restrict__ hn4,
    const float4* __restrict__ ww4, const float4* __restrict__ wb4,
    float4* __restrict__ out4, int n) {
    const size_t gtid = blockIdx.x * (size_t)256 + threadIdx.x;
    const int row = (int)(gtid >> 2);
    const int sub = (int)(gtid & 3);
    if (row >= n) return;

    float4 acc[4];
    #pragma unroll
    for (int m = 0; m < 4; ++m) acc[m] = wb4[sub * 4 + m];

    #pragma unroll 4
    for (int k4 = 0; k4 < 16; ++k4) {
        const float4 xv = h4[(size_t)row * 16 + k4];
        #pragma unroll
        for (int j = 0; j < 4; ++j) {
            const int k = k4 * 4 + j;
            const float xs = (j == 0) ? xv.x : (j == 1) ? xv.y : (j == 2) ? xv.z : xv.w;
            #pragma unroll
            for (int m = 0; m < 4; ++m) {
                const float4 w = ww4[k * 16 + sub * 4 + m];
                acc[m].x = fmaf(xs, w.x, acc[m].x);
                acc[m].y = fmaf(xs, w.y, acc[m].y);
                acc[m].z = fmaf(xs, w.z, acc[m].z);
                acc[m].w = fmaf(xs, w.w, acc[m].w);
            }
        }
    }
    #pragma unroll 4
    for (int k4 = 0; k4 < 16; ++k4) {
        const float4 xv = hn4[(size_t)row * 16 + k4];
        #pragma unroll
        for (int j = 0; j < 4; ++j) {
            const int k = 64 + k4 * 4 + j;
            const float xs = (j == 0) ? xv.x : (j == 1) ? xv.y : (j == 2) ? xv.z : xv.w;
            #pragma unroll
            for (int m = 0; m < 4; ++m) {
                const float4 w = ww4[k * 16 + sub * 4 + m];
                acc[m].x = fmaf(xs, w.x, acc[m].x);
                acc[m].y = fmaf(xs, w.y, acc[m].y);
                acc[m].z = fmaf(xs, w.z, acc[m].z);
                acc[m].w = fmaf(xs, w.w, acc[m].w);
            }
        }
    }

    float sq = 0.f;
    #pragma unroll
    for (int m = 0; m < 4; ++m) {
        acc[m].x = fmaxf(acc[m].x, 0.f); acc[m].y = fmaxf(acc[m].y, 0.f);
        acc[m].z = fmaxf(acc[m].z, 0.f); acc[m].w = fmaxf(acc[m].w, 0.f);
        sq = fmaf(acc[m].x, acc[m].x, sq);
        sq = fmaf(acc[m].y, acc[m].y, sq);
        sq = fmaf(acc[m].z, acc[m].z, sq);
        sq = fmaf(acc[m].w, acc[m].w, sq);
    }
    sq += __shfl_xor(sq, 1, 64);
    sq += __shfl_xor(sq, 2, 64);
    const float inv = 1.0f / sqrtf(sq);

    #pragma unroll
    for (int m = 0; m < 4; ++m) {
        nt_f4 r;
        r.x = acc[m].x * inv; r.y = acc[m].y * inv;
        r.z = acc[m].z * inv; r.w = acc[m].w * inv;
        __builtin_nontemporal_store(r, (nt_f4*)&out4[(size_t)row * 16 + sub * 4 + m]);
    }
}

extern "C" void kernel_launch(void* const* d_in, const int* in_sizes, int n_in,
                              void* d_out, int out_size, void* d_ws, size_t ws_size,
                              hipStream_t stream) {
    const float* feat  = (const float*)d_in[0];
    const float* qw    = (const float*)d_in[1];
    const float* qb    = (const float*)d_in[2];
    const float* ww    = (const float*)d_in[3];
    const float* wb    = (const float*)d_in[4];
    const float* alpha = (const float*)d_in[5];
    const int*   src   = (const int*)d_in[6];
    const int*   dst   = (const int*)d_in[7];
    float* out = (float*)d_out;

    const int n  = in_sizes[0] / IN_DIM;   // 100000
    const int nE = in_sizes[5];            // 1600000
    const int NB = (n + 255) / 256;        // 391

    // workspace layout
    float* h        = (float*)d_ws;                    // n*64 f32
    float* hn       = h + (size_t)n * IN_DIM;          // n*64 f32
    int*   counts   = (int*)(hn + (size_t)n * IN_DIM); // n
    int*   offsets  = counts + n;                      // n+1
    int*   cursor   = offsets + (n + 1);               // n
    int*   blocksums= cursor + n;                      // NB
    int*   srcs_s   = blocksums + NB;                  // nE
    float* alphas_s = (float*)(srcs_s + nE);           // nE
    const size_t needed = (size_t)((char*)(alphas_s + nE) - (char*)d_ws);
    const bool do_csr = ws_size >= needed;

    // 0) canary (attribution probe; writes offsets[n]=nE, harmless)
    canary_kernel<<<1, 64, 0, stream>>>(offsets, n, nE);

    // 1) projection + zero counts
    proj_kernel<<<(int)(((long long)n * 4 + 255) / 256), 256, 0, stream>>>(
        (const float4*)feat, (const float4*)qw, (const float4*)qb,
        (float4*)h, counts, n);

    if (do_csr) {
        // 2) CSR build + atomic-free aggregation (canonical)
        count_kernel<<<(nE + 255) / 256, 256, 0, stream>>>(dst, counts, n, nE);
        scan1_kernel<<<NB, 256, 0, stream>>>(counts, offsets, blocksums, n);
        scan2_kernel<<<1, 512, 0, stream>>>(blocksums, NB);
        scan3_kernel<<<NB, 256, 0, stream>>>(offsets, cursor, blocksums, n, nE);
        fill_kernel<<<(nE + 255) / 256, 256, 0, stream>>>(
            dst, src, alpha, cursor, srcs_s, alphas_s, n, nE);
        agg_kernel<<<(int)(((long long)n * 64 + 255) / 256), 256, 0, stream>>>(
            (const float4*)h, alphas_s, srcs_s, offsets, (float4*)hn, n, nE);
    } else {
        // fallback: zero + atomic scatter
        const size_t cnt = (size_t)n * IN_DIM;
        zero_kernel<<<(int)((cnt + 255) / 256), 256, 0, stream>>>(hn, cnt);
        scatter_kernel<<<(int)(((long long)nE * 16 + 255) / 256), 256, 0, stream>>>(
            (const float4*)h, alpha, src, dst, hn, nE);
    }

    // 3) concat GEMV + ReLU + L2 normalize
    out_kernel<<<(int)(((long long)n * 4 + 255) / 256), 256, 0, stream>>>(
        (const float4*)h, (const float4*)hn, (const float4*)ww,
        (const float4*)wb, (float4*)out, n);
}

// Round 13
// 450.019 us; speedup vs baseline: 5.9613x; 1.4421x over previous
//
#include <hip/hip_runtime.h>
#include <hip/hip_bf16.h>

#define IN_DIM 64
#define OUT_DIM 64

typedef float nt_f4 __attribute__((ext_vector_type(4)));   // for nontemporal builtins

// ---------------------------------------------------------------------------
// Canary: launched FIRST; absorbs any first-dispatch counter-attribution
// artifact (reset/poison traffic). Writes offsets[n]=nE (scan3 rewrites it).
// ---------------------------------------------------------------------------
__global__ void canary_kernel(int* __restrict__ offsets, int n, int nE) {
    if (threadIdx.x == 0 && blockIdx.x == 0) offsets[n] = nE;
}

// ---------------------------------------------------------------------------
// Kernel 1: h = ReLU(features @ q_w + q_b); counts = 0.
// Register-blocked: each thread computes 4 rows x 16 cols; q_w loads
// amortized over 4 rows (round-9 counters: 1-row/thread GEMV was
// on-chip-load-bound, VALU 5.9%, HBM 4.7%).
// ---------------------------------------------------------------------------
__global__ __launch_bounds__(256) void proj_kernel(
    const float4* __restrict__ feat4, const float4* __restrict__ qw4,
    const float4* __restrict__ qb4, float4* __restrict__ h4,
    int* __restrict__ counts, int n) {
    const size_t gtid = blockIdx.x * (size_t)256 + threadIdx.x;
    const int rg   = (int)(gtid >> 2);       // 4-row group
    const int sub  = (int)(gtid & 3);        // 16-col chunk
    const int row0 = rg * 4;
    if (row0 >= n) return;
    const int rmax = (n - row0 < 4) ? (n - row0) : 4;

    float4 acc[4][4];                        // [row][m]
    #pragma unroll
    for (int r = 0; r < 4; ++r)
        #pragma unroll
        for (int m = 0; m < 4; ++m) acc[r][m] = qb4[sub * 4 + m];

    for (int k4 = 0; k4 < 16; ++k4) {
        float4 xv[4];
        #pragma unroll
        for (int r = 0; r < 4; ++r) {
            const int rr = (r < rmax) ? r : 0;
            xv[r] = feat4[(size_t)(row0 + rr) * 16 + k4];
        }
        float4 w[4][4];                      // [j][m]
        #pragma unroll
        for (int j = 0; j < 4; ++j)
            #pragma unroll
            for (int m = 0; m < 4; ++m)
                w[j][m] = qw4[(k4 * 4 + j) * 16 + sub * 4 + m];
        #pragma unroll
        for (int j = 0; j < 4; ++j) {
            #pragma unroll
            for (int r = 0; r < 4; ++r) {
                const float xs = (j == 0) ? xv[r].x : (j == 1) ? xv[r].y
                               : (j == 2) ? xv[r].z : xv[r].w;
                #pragma unroll
                for (int m = 0; m < 4; ++m) {
                    acc[r][m].x = fmaf(xs, w[j][m].x, acc[r][m].x);
                    acc[r][m].y = fmaf(xs, w[j][m].y, acc[r][m].y);
                    acc[r][m].z = fmaf(xs, w[j][m].z, acc[r][m].z);
                    acc[r][m].w = fmaf(xs, w[j][m].w, acc[r][m].w);
                }
            }
        }
    }

    #pragma unroll
    for (int r = 0; r < 4; ++r) {
        if (r >= rmax) break;
        if (sub == 0) counts[row0 + r] = 0;
        #pragma unroll
        for (int m = 0; m < 4; ++m) {
            float4 v = acc[r][m];
            v.x = fmaxf(v.x, 0.f); v.y = fmaxf(v.y, 0.f);
            v.z = fmaxf(v.z, 0.f); v.w = fmaxf(v.w, 0.f);
            h4[(size_t)(row0 + r) * 16 + sub * 4 + m] = v;
        }
    }
}

// ---------------------------------------------------------------------------
// CSR build: histogram of dst
// ---------------------------------------------------------------------------
__global__ __launch_bounds__(256) void count_kernel(
    const int* __restrict__ dst, int* __restrict__ counts, int n, int nE) {
    const int e = blockIdx.x * 256 + threadIdx.x;
    if (e >= nE) return;
    int d = __builtin_nontemporal_load(&dst[e]);
    d = ((unsigned)d < (unsigned)n) ? d : 0;
    atomicAdd(&counts[d], 1);
}

// per-block inclusive scan -> exclusive offsets + block sums
__global__ __launch_bounds__(256) void scan1_kernel(
    const int* __restrict__ counts, int* __restrict__ offsets,
    int* __restrict__ blocksums, int n) {
    __shared__ int s[256];
    const int tid = threadIdx.x;
    const int i = blockIdx.x * 256 + tid;
    const int v = (i < n) ? counts[i] : 0;
    s[tid] = v;
    __syncthreads();
    #pragma unroll
    for (int off = 1; off < 256; off <<= 1) {
        const int t = (tid >= off) ? s[tid - off] : 0;
        __syncthreads();
        s[tid] += t;
        __syncthreads();
    }
    if (i < n) offsets[i] = s[tid] - v;          // exclusive within block
    if (tid == 255) blocksums[blockIdx.x] = s[255];
}

// single-block exclusive scan of block sums (nb <= 512)
__global__ __launch_bounds__(512) void scan2_kernel(int* __restrict__ blocksums, int nb) {
    __shared__ int s[512];
    const int tid = threadIdx.x;
    const int v = (tid < nb) ? blocksums[tid] : 0;
    s[tid] = v;
    __syncthreads();
    #pragma unroll
    for (int off = 1; off < 512; off <<= 1) {
        const int t = (tid >= off) ? s[tid - off] : 0;
        __syncthreads();
        s[tid] += t;
        __syncthreads();
    }
    if (tid < nb) blocksums[tid] = s[tid] - v;   // exclusive
}

__global__ __launch_bounds__(256) void scan3_kernel(
    int* __restrict__ offsets, int* __restrict__ cursor,
    const int* __restrict__ blocksums, int n, int nE) {
    const int i = blockIdx.x * 256 + threadIdx.x;
    if (i < n) {
        const int o = offsets[i] + blocksums[blockIdx.x];
        offsets[i] = o;
        cursor[i]  = o;
    }
    if (i == 0) offsets[n] = nE;
}

// bucket edges by dst: pack {src, alpha} into ONE int2 (8B) scattered store
// (round-9 version: two 4B stores to two arrays = 2 random cache-line
// touches per edge; this halves them).
__global__ __launch_bounds__(256) void fill_kernel(
    const int* __restrict__ dst, const int* __restrict__ src,
    const float* __restrict__ alpha, int* __restrict__ cursor,
    int2* __restrict__ edges_s, int n, int nE) {
    const int e = blockIdx.x * 256 + threadIdx.x;
    if (e >= nE) return;
    int d = __builtin_nontemporal_load(&dst[e]);
    d = ((unsigned)d < (unsigned)n) ? d : 0;
    const int s = __builtin_nontemporal_load(&src[e]);
    const float a = __builtin_nontemporal_load(&alpha[e]);
    const int p = atomicAdd(&cursor[d], 1);
    if ((unsigned)p < (unsigned)nE) {
        edges_s[p] = make_int2(s, __float_as_int(a));
    }
}

// ---------------------------------------------------------------------------
// Aggregation (atomic-free): one wave per node; 4 edges in parallel
// (quarter-wave = 16 lanes x float4 per edge -> 4 independent gather chains).
// ---------------------------------------------------------------------------
__global__ __launch_bounds__(256) void agg_kernel(
    const float4* __restrict__ h4, const int2* __restrict__ edges_s,
    const int* __restrict__ offsets, float4* __restrict__ hn4, int n, int nE) {
    const size_t gtid = blockIdx.x * (size_t)256 + threadIdx.x;
    const int v    = (int)(gtid >> 6);
    const int lane = (int)(gtid & 63);
    const int q    = lane >> 4;        // quarter: which of 4 parallel edges
    const int c4   = lane & 15;        // float4 chunk of the 64-dim row
    if (v >= n) return;

    int b  = offsets[v];
    int e1 = offsets[v + 1];
    if (b < 0) b = 0;
    if (e1 > nE) e1 = nE;

    float4 acc = make_float4(0.f, 0.f, 0.f, 0.f);
    for (int j = b + q; j < e1; j += 4) {
        const int2 ed = edges_s[j];
        int s = ed.x;
        s = ((unsigned)s < (unsigned)n) ? s : 0;
        const float a = __int_as_float(ed.y);
        const float4 hv = h4[(size_t)s * 16 + c4];
        acc.x = fmaf(hv.x, a, acc.x);
        acc.y = fmaf(hv.y, a, acc.y);
        acc.z = fmaf(hv.z, a, acc.z);
        acc.w = fmaf(hv.w, a, acc.w);
    }
    // reduce the 4 quarter-wave partials (lanes ^16, ^32): same dims per quarter
    acc.x += __shfl_xor(acc.x, 16, 64); acc.y += __shfl_xor(acc.y, 16, 64);
    acc.z += __shfl_xor(acc.z, 16, 64); acc.w += __shfl_xor(acc.w, 16, 64);
    acc.x += __shfl_xor(acc.x, 32, 64); acc.y += __shfl_xor(acc.y, 32, 64);
    acc.z += __shfl_xor(acc.z, 32, 64); acc.w += __shfl_xor(acc.w, 32, 64);

    if (q == 0) hn4[(size_t)v * 16 + c4] = acc;
}

// ---------------------------------------------------------------------------
// Fallback (only if ws too small): atomic scatter. hn must be pre-zeroed.
// ---------------------------------------------------------------------------
__global__ __launch_bounds__(256) void zero_kernel(float* __restrict__ p, size_t cnt) {
    const size_t i = blockIdx.x * (size_t)256 + threadIdx.x;
    if (i < cnt) p[i] = 0.f;
}
__global__ __launch_bounds__(256) void scatter_kernel(
    const float4* __restrict__ h4, const float* __restrict__ alpha,
    const int* __restrict__ src, const int* __restrict__ dst,
    float* __restrict__ hn, int nE) {
    const size_t gtid = blockIdx.x * (size_t)256 + threadIdx.x;
    const int eid = (int)(gtid >> 4);
    const int c4  = (int)(gtid & 15);
    if (eid >= nE) return;
    const int   s = src[eid];
    const int   d = dst[eid];
    const float a = alpha[eid];
    const float4 v = h4[(size_t)s * 16 + c4];
    float* p = &hn[(size_t)d * IN_DIM + c4 * 4];
    unsafeAtomicAdd(p + 0, v.x * a);
    unsafeAtomicAdd(p + 1, v.y * a);
    unsafeAtomicAdd(p + 2, v.z * a);
    unsafeAtomicAdd(p + 3, v.w * a);
}

// ---------------------------------------------------------------------------
// Kernel 3: z = ReLU(concat([h, hn]) @ w_w + w_b); out = z / ||z||_2.
// Register-blocked 4 rows x 16 cols per thread: w_w loads amortized 4x.
// ---------------------------------------------------------------------------
__global__ __launch_bounds__(256) void out_kernel(
    const float4* __restrict__ h4, const float4* __restrict__ hn4,
    const float4* __restrict__ ww4, const float4* __restrict__ wb4,
    float4* __restrict__ out4, int n) {
    const size_t gtid = blockIdx.x * (size_t)256 + threadIdx.x;
    const int rg   = (int)(gtid >> 2);
    const int sub  = (int)(gtid & 3);
    const int row0 = rg * 4;
    if (row0 >= n) return;
    const int rmax = (n - row0 < 4) ? (n - row0) : 4;

    float4 acc[4][4];
    #pragma unroll
    for (int r = 0; r < 4; ++r)
        #pragma unroll
        for (int m = 0; m < 4; ++m) acc[r][m] = wb4[sub * 4 + m];

    // phase 0: h @ w_w[0:64];  phase 1: hn @ w_w[64:128]
    #pragma unroll
    for (int ph = 0; ph < 2; ++ph) {
        const float4* __restrict__ x4 = (ph == 0) ? h4 : hn4;
        for (int k4 = 0; k4 < 16; ++k4) {
            float4 xv[4];
            #pragma unroll
            for (int r = 0; r < 4; ++r) {
                const int rr = (r < rmax) ? r : 0;
                xv[r] = x4[(size_t)(row0 + rr) * 16 + k4];
            }
            float4 w[4][4];
            #pragma unroll
            for (int j = 0; j < 4; ++j)
                #pragma unroll
                for (int m = 0; m < 4; ++m)
                    w[j][m] = ww4[(ph * 64 + k4 * 4 + j) * 16 + sub * 4 + m];
            #pragma unroll
            for (int j = 0; j < 4; ++j) {
                #pragma unroll
                for (int r = 0; r < 4; ++r) {
                    const float xs = (j == 0) ? xv[r].x : (j == 1) ? xv[r].y
                                   : (j == 2) ? xv[r].z : xv[r].w;
                    #pragma unroll
                    for (int m = 0; m < 4; ++m) {
                        acc[r][m].x = fmaf(xs, w[j][m].x, acc[r][m].x);
                        acc[r][m].y = fmaf(xs, w[j][m].y, acc[r][m].y);
                        acc[r][m].z = fmaf(xs, w[j][m].z, acc[r][m].z);
                        acc[r][m].w = fmaf(xs, w[j][m].w, acc[r][m].w);
                    }
                }
            }
        }
    }

    // ReLU + per-row sum of squares; reduce across the 4 subs (lanes ^1, ^2)
    float sq[4];
    #pragma unroll
    for (int r = 0; r < 4; ++r) {
        float s = 0.f;
        #pragma unroll
        for (int m = 0; m < 4; ++m) {
            acc[r][m].x = fmaxf(acc[r][m].x, 0.f);
            acc[r][m].y = fmaxf(acc[r][m].y, 0.f);
            acc[r][m].z = fmaxf(acc[r][m].z, 0.f);
            acc[r][m].w = fmaxf(acc[r][m].w, 0.f);
            s = fmaf(acc[r][m].x, acc[r][m].x, s);
            s = fmaf(acc[r][m].y, acc[r][m].y, s);
            s = fmaf(acc[r][m].z, acc[r][m].z, s);
            s = fmaf(acc[r][m].w, acc[r][m].w, s);
        }
        sq[r] = s;
    }
    #pragma unroll
    for (int r = 0; r < 4; ++r) {
        sq[r] += __shfl_xor(sq[r], 1, 64);
        sq[r] += __shfl_xor(sq[r], 2, 64);
    }

    #pragma unroll
    for (int r = 0; r < 4; ++r) {
        if (r >= rmax) break;
        const float inv = 1.0f / sqrtf(sq[r]);
        #pragma unroll
        for (int m = 0; m < 4; ++m) {
            nt_f4 v;
            v.x = acc[r][m].x * inv; v.y = acc[r][m].y * inv;
            v.z = acc[r][m].z * inv; v.w = acc[r][m].w * inv;
            __builtin_nontemporal_store(
                v, (nt_f4*)&out4[(size_t)(row0 + r) * 16 + sub * 4 + m]);
        }
    }
}

extern "C" void kernel_launch(void* const* d_in, const int* in_sizes, int n_in,
                              void* d_out, int out_size, void* d_ws, size_t ws_size,
                              hipStream_t stream) {
    const float* feat  = (const float*)d_in[0];
    const float* qw    = (const float*)d_in[1];
    const float* qb    = (const float*)d_in[2];
    const float* ww    = (const float*)d_in[3];
    const float* wb    = (const float*)d_in[4];
    const float* alpha = (const float*)d_in[5];
    const int*   src   = (const int*)d_in[6];
    const int*   dst   = (const int*)d_in[7];
    float* out = (float*)d_out;

    const int n  = in_sizes[0] / IN_DIM;   // 100000
    const int nE = in_sizes[5];            // 1600000
    const int NB = (n + 255) / 256;        // 391

    // workspace layout
    float* h        = (float*)d_ws;                    // n*64 f32
    float* hn       = h + (size_t)n * IN_DIM;          // n*64 f32
    int*   counts   = (int*)(hn + (size_t)n * IN_DIM); // n
    int*   offsets  = counts + n;                      // n+1
    int*   cursor   = offsets + (n + 1);               // n
    int*   blocksums= cursor + n;                      // NB
    // align edges_s to 8B
    char*  raw      = (char*)(blocksums + NB);
    int2*  edges_s  = (int2*)(((uintptr_t)raw + 7) & ~(uintptr_t)7);   // nE int2
    const size_t needed = (size_t)((char*)(edges_s + nE) - (char*)d_ws);
    const bool do_csr = ws_size >= needed;

    // 0) canary (attribution probe)
    canary_kernel<<<1, 64, 0, stream>>>(offsets, n, nE);

    // 1) projection + zero counts (4 rows x 16 cols per thread)
    {
        const long long t = ((long long)(n + 3) / 4) * 4;
        proj_kernel<<<(int)((t + 255) / 256), 256, 0, stream>>>(
            (const float4*)feat, (const float4*)qw, (const float4*)qb,
            (float4*)h, counts, n);
    }

    if (do_csr) {
        // 2) CSR build + atomic-free aggregation (canonical)
        count_kernel<<<(nE + 255) / 256, 256, 0, stream>>>(dst, counts, n, nE);
        scan1_kernel<<<NB, 256, 0, stream>>>(counts, offsets, blocksums, n);
        scan2_kernel<<<1, 512, 0, stream>>>(blocksums, NB);
        scan3_kernel<<<NB, 256, 0, stream>>>(offsets, cursor, blocksums, n, nE);
        fill_kernel<<<(nE + 255) / 256, 256, 0, stream>>>(
            dst, src, alpha, cursor, edges_s, n, nE);
        agg_kernel<<<(int)(((long long)n * 64 + 255) / 256), 256, 0, stream>>>(
            (const float4*)h, edges_s, offsets, (float4*)hn, n, nE);
    } else {
        // fallback: zero + atomic scatter
        const size_t cnt = (size_t)n * IN_DIM;
        zero_kernel<<<(int)((cnt + 255) / 256), 256, 0, stream>>>(hn, cnt);
        scatter_kernel<<<(int)(((long long)nE * 16 + 255) / 256), 256, 0, stream>>>(
            (const float4*)h, alpha, src, dst, hn, nE);
    }

    // 3) concat GEMV + ReLU + L2 normalize (4 rows x 16 cols per thread)
    {
        const long long t = ((long long)(n + 3) / 4) * 4;
        out_kernel<<<(int)((t + 255) / 256), 256, 0, stream>>>(
            (const float4*)h, (const float4*)hn, (const float4*)ww,
            (const float4*)wb, (float4*)out, n);
    }
}